// Round 22
// baseline (200.640 us; speedup 1.0000x reference)
//
#include <hip/hip_runtime.h>
#include <math.h>

#define HH 512
#define WW 512
#define HW (HH*WW)          // 262144
#define BATCH 4
#define NCH 18              // simulated channels (18,19 overwritten at end)
#define BHW (BATCH*HW)

__device__ __constant__ int cDG[8] = {-512,-511,1,513,512,511,-1,-513}; // dy*WW+dx
__device__ __constant__ int cDT[8] = {-48,-47,1,49,48,47,-1,-49};       // dy*ATP+dx

// bucket (3 bits) | enough (bit 3); zeroes list counter
__global__ __launch_bounds__(256) void bv_bucket_kernel(
    const float* __restrict__ vel, unsigned char* __restrict__ bk,
    unsigned* __restrict__ pcount)
{
    int idx = blockIdx.x*256 + threadIdx.x;
    if (idx == 0) { pcount[0] = 0; pcount[1] = 0; }
    if (idx >= BHW) return;
    int b = idx >> 18;
    int rem = idx & (HW-1);
    const float* vb = vel + (size_t)b*2*HW;
    float vy = vb[rem];
    float vx = vb[HW + rem];
    float a2 = vy*vy;
    float b2 = vx*vx;
    float mag = sqrtf(a2 + b2);
    float xx = vx / (mag + 0.001f);
    float af = (float)acos((double)xx);
    const float inv2pi = (float)(1.0/(2.0*3.14159265358979323846));
    float raw = inv2pi * af;
    float ang = (vy < 0.0f) ? (1.0f - raw) : raw;
    float t = ang * 8.0f + 0.5f;
    int bkt = (int)floorf(t);
    bkt &= 7;
    unsigned char e = (mag > 0.1f) ? (unsigned char)8 : (unsigned char)0;
    bk[idx] = (unsigned char)(bkt | e);
}

#define ATP 48
#define ATC (48*48)   // 2304 = 4*512 + 256
#define ANT 512
#define PAD 49        // max |doff|; pads replace index clamps

// ---- Kernel A: fused mask+evolve+vdelta with PADDED LDS. Emits combined
//      MS = m | (sb<<8), vdelta (exact per-step order), and for iter1 the
//      next-iteration bucket byte. COMPOSE=false (iter1): plain records.
//      COMPOSE=true (iter2): composes with Src1; trees to compacted list.
template<bool COMPOSE>
__global__ __launch_bounds__(ANT) void bv_mask_kernel(
    const float* __restrict__ Win, int Cin,
    float* __restrict__ Wout, int Cout,
    const unsigned char* __restrict__ bkall,
    unsigned short* __restrict__ MSg,
    int* __restrict__ SrcOut,
    const float* __restrict__ velg,    // iteration-start velocity
    float* __restrict__ vdout,         // velocity after this iteration
    unsigned char* __restrict__ bkout, // iter1 only: bucket for iter2
    const int* __restrict__ Src1g,     // COMPOSE only
    unsigned* __restrict__ pcount,     // [1]=tree entries (COMPOSE only)
    uint2* __restrict__ tlist,
    unsigned listcap,
    const float* __restrict__ elem_empty)
{
    // carve: A0|A1|B0|B1 (2402 floats each) | KSH (2402 B) | sCnt
    __shared__ __align__(16) unsigned char SHM[40864];
    float* A0  = ((float*)(SHM +     0)) + PAD;
    float* A1  = ((float*)(SHM +  9608)) + PAD;
    float* B0F = ((float*)(SHM + 19216)) + PAD;
    float* B1F = ((float*)(SHM + 28824)) + PAD;
    unsigned char* KSH = SHM + 38432 + PAD;
    unsigned* sCnt = (unsigned*)(SHM + 40840);

    unsigned char* MSHb = SHM + 19216 + PAD;   // post-steps M bytes (B0F dead)
    unsigned char* SBb  = SHM + 28824 + PAD;   // post-steps SB bytes (B1F dead)

    const int tid = threadIdx.x;
    const int blk = blockIdx.x;
    const int tx = blk & 15, ty = (blk >> 4) & 15, b = blk >> 8;
    const int x0 = tx*32 - 8, y0 = ty*32 - 8;

    const float* inb  = Win  + (size_t)b*Cin*HW;
    float*       outb = Wout + (size_t)b*Cout*HW;
    const unsigned char* bkb = bkall + ((size_t)b << 18);
    unsigned short* MSob = MSg + ((size_t)b << 18);
    int*            Srb  = SrcOut + ((size_t)b << 18);
    const float* velb = velg  + (size_t)b*2*HW;
    float*       vdb  = vdout + (size_t)b*2*HW;

    const float e0 = elem_empty[0];
    const float e1 = elem_empty[1];

    float v0r[4], v1r[4];
    unsigned kreg[4], mreg[4];
    unsigned mtail = 0;

    if (tid == 0) sCnt[0] = 0;

    // ---- load: LDS + register copies for owned cells ----
    #pragma unroll
    for (int k = 0; k < 4; ++k) {
        int l = tid + (k << 9);
        int ly = l / ATP, lx = l - ly*ATP;
        int gy = y0 + ly, gx = x0 + lx;
        bool in = ((unsigned)gy < HH) && ((unsigned)gx < WW);
        int g = gy*WW + gx;
        float v0 = 0.f, v1 = 0.f; unsigned char kk = 0;
        if (in) { v0 = inb[g]; v1 = inb[HW + g]; kk = bkb[g]; }
        A0[l] = v0; A1[l] = v1; KSH[l] = kk;
        v0r[k] = v0; v1r[k] = v1; kreg[k] = kk; mreg[k] = 0;
    }
    if (tid < 256) {    // tail cells: LDS-resident values, register M
        int l = 2048 + tid;
        int ly = l / ATP, lx = l - ly*ATP;
        int gy = y0 + ly, gx = x0 + lx;
        bool in = ((unsigned)gy < HH) && ((unsigned)gx < WW);
        int g = gy*WW + gx;
        float v0 = 0.f, v1 = 0.f; unsigned char kk = 0;
        if (in) { v0 = inb[g]; v1 = inb[HW + g]; kk = bkb[g]; }
        A0[l] = v0; A1[l] = v1; KSH[l] = kk;
    }
    __syncthreads();

    // ---- 8 fused steps, one barrier each; unclamped padded access ----
    #pragma unroll
    for (int a = 0; a < 8; ++a) {
        const int doff = cDT[a];
        const unsigned tgt = (unsigned)(a | 8);
        const float* cA0 = (a & 1) ? B0F : A0;
        const float* cA1 = (a & 1) ? B1F : A1;
        float* nA0 = (a & 1) ? A0 : B0F;
        float* nA1 = (a & 1) ? A1 : B1F;
        #pragma unroll
        for (int k = 0; k < 4; ++k) {
            const int l = tid + (k << 9);
            const int ln = l + doff;
            const int lo = l - doff;
            float a0l = v0r[k], a1l = v1r[k];
            float a0n = cA0[ln];
            float a0o = cA0[lo], a1o = cA1[lo];
            unsigned ko = KSH[lo];
            bool sal = ((kreg[k] & 15u) == tgt) & (a0n > 0.5f) & !(a1l > 0.5f);
            bool sao = ((ko & 15u) == tgt) & (a0l > 0.5f) & !(a1o > 0.5f);
            mreg[k] |= (sal ? 1u : 0u) << a;
            float sa = sal ? 1.0f : 0.0f;
            float sb = sao ? 1.0f : 0.0f;
            float r0 = a0l - sa*a0l; r0 = r0 - sb*a0l; r0 = r0 + sa*e0; r0 = r0 + sb*a0o;
            float r1 = a1l - sa*a1l; r1 = r1 - sb*a1l; r1 = r1 + sa*e1; r1 = r1 + sb*a1o;
            v0r[k] = r0; v1r[k] = r1;
            nA0[l] = r0; nA1[l] = r1;
        }
        if (tid < 256) {
            const int l = 2048 + tid;
            const int ln = l + doff;
            const int lo = l - doff;
            float a0l = cA0[l], a1l = cA1[l];
            float a0n = cA0[ln];
            float a0o = cA0[lo], a1o = cA1[lo];
            unsigned kl = KSH[l], ko = KSH[lo];
            bool sal = ((kl & 15u) == tgt) & (a0n > 0.5f) & !(a1l > 0.5f);
            bool sao = ((ko & 15u) == tgt) & (a0l > 0.5f) & !(a1o > 0.5f);
            if (sal) mtail |= 1u << a;
            float sa = sal ? 1.0f : 0.0f;
            float sb = sao ? 1.0f : 0.0f;
            float r0 = a0l - sa*a0l; r0 = r0 - sb*a0l; r0 = r0 + sa*e0; r0 = r0 + sb*a0o;
            float r1 = a1l - sa*a1l; r1 = r1 - sb*a1l; r1 = r1 + sa*e1; r1 = r1 + sb*a1o;
            nA0[l] = r0; nA1[l] = r1;
        }
        __syncthreads();
    }
    // final ch0/ch1 in A0/A1; B0F/B1F dead -> M/SB byte arrays

    #pragma unroll
    for (int k = 0; k < 4; ++k) MSHb[tid + (k << 9)] = (unsigned char)mreg[k];
    if (tid < 256) MSHb[2048 + tid] = (unsigned char)mtail;
    __syncthreads();

    // SB bits (padded MSHb read, no clamps)
    for (int l = tid; l < ATC; l += ANT) {
        unsigned sb8 = 0;
        #pragma unroll
        for (int a = 0; a < 8; ++a) {
            int lo = l - cDT[a];
            sb8 |= (unsigned)((MSHb[lo] >> a) & 1) << a;
        }
        SBb[l] = (unsigned char)sb8;
    }
    __syncthreads();

    // ---- pass A: interior writes + fused vdelta + walk (+composition) ----
    int tNeed[2]; unsigned tLL[2], tEy[2];
    #pragma unroll
    for (int it = 0; it < 2; ++it) {
        tNeed[it] = 0;
        int li = tid + (it << 9);
        int iy = li >> 5, ix = li & 31;
        int l = (iy + 8)*ATP + ix + 8;
        int gy = ty*32 + iy, gx = tx*32 + ix;
        int g = gy*WW + gx;
        outb[g]      = A0[l];
        outb[HW + g] = A1[l];
        unsigned mm = MSHb[l], sbb = SBb[l];
        MSob[g] = (unsigned short)(mm | (sbb << 8));

        // vdelta (exact per-step op order; vel fixed during iteration)
        {
            float vy = velb[g], vx = velb[HW + g];
            float ddy = vy, ddx = vx;
            unsigned act = mm | sbb;
            if (act) {
                #pragma unroll
                for (int a = 0; a < 8; ++a) {
                    if ((act >> a) & 1) {
                        float sa = (float)((mm  >> a) & 1);
                        float sb = (float)((sbb >> a) & 1);
                        float voy = 0.f, vox = 0.f;
                        if (sb != 0.f) {
                            int go = g - cDG[a];     // in-image when sb=1
                            voy = velb[go]; vox = velb[HW + go];
                        }
                        ddy = ddy - (sa*vy)*0.5f; ddy = ddy + (sb*voy)*0.5f;
                        ddx = ddx - (sa*vx)*0.5f; ddx = ddx + (sb*vox)*0.5f;
                    }
                }
            }
            vdb[g]      = ddy;
            vdb[HW + g] = ddx;
            if constexpr (!COMPOSE) {   // emit iter2 bucket byte
                float a2 = ddy*ddy;
                float b2 = ddx*ddx;
                float mag = sqrtf(a2 + b2);
                float xx = ddx / (mag + 0.001f);
                float af = (float)acos((double)xx);
                const float inv2pi = (float)(1.0/(2.0*3.14159265358979323846));
                float raw = inv2pi * af;
                float ang = (ddy < 0.0f) ? (1.0f - raw) : raw;
                float t = ang * 8.0f + 0.5f;
                int bkt = (int)floorf(t);
                bkt &= 7;
                unsigned char e = (mag > 0.1f) ? (unsigned char)8 : (unsigned char)0;
                bkout[((size_t)b << 18) + g] = (unsigned char)(bkt | e);
            }
        }

        // provenance walk in LDS (in-tile by ring invariant)
        int cc = l, ss = 7, kd = 0;
        unsigned m = mm, sb = sbb;
        while (true) {
            unsigned evt = (m | sb) & ((2u << ss) - 1u);
            if (!evt) { kd = 0; break; }
            int bb = 31 - __builtin_clz(evt);
            int ia = (m >> bb) & 1, ib = (sb >> bb) & 1;
            if (ia && ib) { kd = 2; break; }        // tree at (cc, ss)
            if (ia) { kd = 1; break; }              // e=0 for c>=2 -> ZERO
            cc -= cDT[bb]; ss = bb - 1;             // sb-only: exact value move
            if (ss < 0) { kd = 0; break; }
            m = MSHb[cc]; sb = SBb[cc];
        }
        if (kd == 1) {
            Srb[g] = (int)(1u << 30);
        } else if (kd == 0) {
            int cly = cc / ATP, clx = cc - cly*ATP;
            unsigned s = (unsigned)((y0 + cly)*WW + (x0 + clx));
            if (!COMPOSE) {
                Srb[g] = (int)s;
            } else {
                unsigned r1 = (unsigned)Src1g[((size_t)b << 18) + s];
                unsigned k1 = r1 >> 30;
                if (k1 == 0u)      Srb[g] = (int)r1;        // copy o copy
                else if (k1 == 1u) Srb[g] = (int)(1u << 30);
                else { tNeed[it] = 1; tEy[it] = s; }        // type B: tree1 @ s
            }
        } else {
            if (!COMPOSE) {
                Srb[g] = (int)(2u << 30);   // lazy tree1 marker
            } else {
                int cly = cc / ATP, clx = cc - cly*ATP;
                unsigned ccg = (unsigned)((y0 + cly)*WW + (x0 + clx));
                tNeed[it] = 1;
                tEy[it] = (1u << 31) | ((unsigned)ss << 28) | ccg;   // type A
            }
        }
        if (COMPOSE && tNeed[it]) tLL[it] = atomicAdd(&sCnt[0], 1u);
    }
    if constexpr (COMPOSE) {
        __syncthreads();
        if (tid == 0) sCnt[1] = sCnt[0] ? atomicAdd(&pcount[1], sCnt[0]) : 0u;
        __syncthreads();
        unsigned lbase = sCnt[1];
        #pragma unroll
        for (int it = 0; it < 2; ++it) {
            if (!tNeed[it]) continue;
            int li = tid + (it << 9);
            int iy = li >> 5, ix = li & 31;
            int g = (ty*32 + iy)*WW + tx*32 + ix;
            unsigned lidx = lbase + tLL[it];
            if (lidx < listcap) {
                tlist[lidx] = make_uint2(((unsigned)b << 18) | (unsigned)g, tEy[it]);
                Srb[g] = (int)(2u << 30);           // placeholder
            } else {
                Srb[g] = (int)(3u << 30);           // unreachable (cap 16x margin)
            }
        }
    }
}

// ---- iterative stack-machine evaluator on MS, DIRECT leaves. Depth <= 9.
__device__ __attribute__((noinline)) float bv_eval(
    int cell, int stp,
    const unsigned short* __restrict__ MS,
    const float* __restrict__ initc)
{
    float vstk[10]; int vsp = 0;
    int cs_cell[10], cs_stp[10], cs_ph[10]; int csp = 0;
    cs_cell[0] = cell; cs_stp[0] = stp; cs_ph[0] = 0; csp = 1;
    while (csp > 0) {
        int ph = cs_ph[csp-1];
        if (ph == 0) {
            int cc = cs_cell[csp-1], ss = cs_stp[csp-1];
            float result = 0.0f; int have = 0;
            while (true) {
                if (ss < 0) { result = initc[cc]; have = 1; break; }
                unsigned v = MS[cc];
                unsigned m = v & 255u, sb = v >> 8;
                unsigned evt = (m | sb) & ((2u << ss) - 1u);
                if (!evt) { result = initc[cc]; have = 1; break; }
                int bb = 31 - __builtin_clz(evt);
                int ia = (m >> bb) & 1, ib = (sb >> bb) & 1;
                if (ia && ib) {
                    cs_cell[csp-1] = cc; cs_stp[csp-1] = bb; cs_ph[csp-1] = 1;
                    cs_cell[csp] = cc - cDG[bb]; cs_stp[csp] = bb - 1; cs_ph[csp] = 0; csp++;
                    break;
                }
                if (ia) { result = 0.0f; have = 1; break; }
                cc -= cDG[bb]; ss = bb - 1;
            }
            if (have) { vstk[vsp++] = result; csp--; }
        } else if (ph == 1) {
            cs_ph[csp-1] = 2;
            cs_cell[csp] = cs_cell[csp-1]; cs_stp[csp] = cs_stp[csp-1] - 1;
            cs_ph[csp] = 0; csp++;
        } else {
            float Bv = vstk[--vsp]; float Av = vstk[--vsp];
            vstk[vsp++] = Av - Bv;   // fl(wo - w)
            csp--;
        }
    }
    return vstk[0];
}

// iter1 value at cell L, one channel (walk MS1; rare tree -> bv_eval)
__device__ float bv_leaf1_1(int L,
    const unsigned short* __restrict__ MS1,
    const float* __restrict__ ic)
{
    int cc = L, ss = 7;
    while (true) {
        unsigned v = MS1[cc];
        unsigned m = v & 255u, sb = v >> 8;
        unsigned evt = (m | sb) & ((2u << ss) - 1u);
        if (!evt) break;                        // value = input at cc
        int bb = 31 - __builtin_clz(evt);
        int ia = (m >> bb) & 1, ib = (sb >> bb) & 1;
        if (ia && ib) return bv_eval(cc, bb, MS1, ic);   // tree1
        if (ia) return 0.0f;
        cc -= cDG[bb]; ss = bb - 1;
        if (ss < 0) break;                      // value = input at cc
    }
    return ic[cc];
}

// iterative evaluator on MS2 with leaves INDIRECTED through iter1.
__device__ float bv_eval1_ind(int cell, int stp,
    const unsigned short* __restrict__ MS2,
    const unsigned short* __restrict__ MS1,
    const float* __restrict__ ic)
{
    float vstk[10]; int vsp = 0;
    int cs_cell[10], cs_stp[10], cs_ph[10]; int csp = 0;
    cs_cell[0] = cell; cs_stp[0] = stp; cs_ph[0] = 0; csp = 1;
    while (csp > 0) {
        int ph = cs_ph[csp-1];
        if (ph == 0) {
            int cc = cs_cell[csp-1], ss = cs_stp[csp-1];
            int have = 0, zero = 0, leaf = 0;
            while (true) {
                if (ss < 0) { leaf = cc; have = 1; break; }
                unsigned v = MS2[cc];
                unsigned m = v & 255u, sb = v >> 8;
                unsigned evt = (m | sb) & ((2u << ss) - 1u);
                if (!evt) { leaf = cc; have = 1; break; }
                int bb = 31 - __builtin_clz(evt);
                int ia = (m >> bb) & 1, ib = (sb >> bb) & 1;
                if (ia && ib) {
                    cs_cell[csp-1] = cc; cs_stp[csp-1] = bb; cs_ph[csp-1] = 1;
                    cs_cell[csp] = cc - cDG[bb]; cs_stp[csp] = bb - 1; cs_ph[csp] = 0; csp++;
                    break;
                }
                if (ia) { zero = 1; have = 1; break; }
                cc -= cDG[bb]; ss = bb - 1;
            }
            if (have) {
                vstk[vsp++] = zero ? 0.0f : bv_leaf1_1(leaf, MS1, ic);
                csp--;
            }
        } else if (ph == 1) {
            cs_ph[csp-1] = 2;
            cs_cell[csp] = cs_cell[csp-1]; cs_stp[csp] = cs_stp[csp-1] - 1;
            cs_ph[csp] = 0; csp++;
        } else {
            float Bv = vstk[--vsp]; float Av = vstk[--vsp];
            vstk[vsp++] = Av - Bv;
            csp--;
        }
    }
    return vstk[0];
}

// ---- Kernel B: apply composed provenance world_in -> out.
//      8 pixels/thread; slow path batches ALL loads (4ch x (2xfloat4 +
//      8 gathers)) before any store -> max MLP. Non-copy lanes write 0.
__global__ __launch_bounds__(256) void bv_apply_kernel(
    const float* __restrict__ Win, int Cin,
    float* __restrict__ Wout, int Cout,
    const int* __restrict__ Src)
{
    int t = blockIdx.x*256 + threadIdx.x;   // over BHW/8
    if (t >= BHW/8) return;
    const int c0 = 2 + blockIdx.y*4;        // channel group [c0, c0+4)
    int p = t << 3;
    int b = p >> 18;
    int own = p & (HW-1);
    const float* inb  = Win  + (size_t)b*Cin*HW;
    float*       outb = Wout + (size_t)b*Cout*HW;
    const int* Srb = Src + ((size_t)b << 18);

    int4 sA = *(const int4*)(Srb + own);
    int4 sB = *(const int4*)(Srb + own + 4);
    unsigned sv[8] = {(unsigned)sA.x, (unsigned)sA.y, (unsigned)sA.z, (unsigned)sA.w,
                      (unsigned)sB.x, (unsigned)sB.y, (unsigned)sB.z, (unsigned)sB.w};
    int kind[8], idx[8]; bool need[8];
    bool allself = true;
    #pragma unroll
    for (int j = 0; j < 8; ++j) {
        kind[j] = (int)(sv[j] >> 30);
        idx[j]  = (int)(sv[j] & 0x3FFFFu);
        need[j] = (kind[j] != 0) || (idx[j] != own + j);
        allself = allself && !need[j];
    }

    if (allself) {
        #pragma unroll
        for (int c = 0; c < 4; ++c) {
            const float* ic = inb + (size_t)(c0 + c)*HW;
            float*       oc = outb + (size_t)(c0 + c)*HW;
            float4 va = *(const float4*)(ic + own);
            float4 vb = *(const float4*)(ic + own + 4);
            *(float4*)(oc + own)     = va;
            *(float4*)(oc + own + 4) = vb;
        }
        return;
    }
    // slow path: load everything first (static indices), then store
    float r[4][8];
    #pragma unroll
    for (int c = 0; c < 4; ++c) {
        const float* ic = inb + (size_t)(c0 + c)*HW;
        float4 va = *(const float4*)(ic + own);
        float4 vb = *(const float4*)(ic + own + 4);
        r[c][0] = va.x; r[c][1] = va.y; r[c][2] = va.z; r[c][3] = va.w;
        r[c][4] = vb.x; r[c][5] = vb.y; r[c][6] = vb.z; r[c][7] = vb.w;
        #pragma unroll
        for (int j = 0; j < 8; ++j) {
            if (need[j])
                r[c][j] = (kind[j] == 0) ? ic[idx[j]] : 0.0f;  // 1/2/3 -> 0
        }
    }
    #pragma unroll
    for (int c = 0; c < 4; ++c) {
        float* oc = outb + (size_t)(c0 + c)*HW;
        *(float4*)(oc + own)     = make_float4(r[c][0], r[c][1], r[c][2], r[c][3]);
        *(float4*)(oc + own + 4) = make_float4(r[c][4], r[c][5], r[c][6], r[c][7]);
    }
}

// ---- Kernel C: composed tree cells; 32 threads/entry:
//      (channel, half) pairs — even lane evals A-subtree, odd lane B;
//      combine A-B via shfl_xor. Halves the serial straggler chain.
__global__ __launch_bounds__(256) void bv_tree_kernel(
    const float* __restrict__ Win,       // world_in, 20-ch
    float* __restrict__ Wout,            // out, 20-ch
    const uint2* __restrict__ tlist,
    const unsigned* __restrict__ pcount, // [1] = entry count
    unsigned listcap,
    const unsigned short* __restrict__ MS1,
    const unsigned short* __restrict__ MS2)
{
    unsigned n = pcount[1]; if (n > listcap) n = listcap;
    unsigned total = n * 32;
    for (unsigned i = blockIdx.x*256 + threadIdx.x; i < total; i += gridDim.x*256) {
        unsigned ei = i >> 5;
        int c = 2 + (int)((i >> 1) & 15);
        int h = (int)(i & 1);
        uint2 e = tlist[ei];
        int b = (int)((e.x >> 18) & 3u);
        int g = (int)(e.x & 0x3FFFFu);
        const float* ic = Win  + (size_t)b*20*HW + (size_t)c*HW;
        float*       oc = Wout + (size_t)b*20*HW + (size_t)c*HW;
        const unsigned short* MS1b = MS1 + ((size_t)b << 18);
        float val = 0.0f;
        if (e.y >> 31) {        // type A: tree2 at (cc, bound ss)
            int cc = (int)(e.y & 0x3FFFFu);
            int ss = (int)((e.y >> 28) & 7u);
            const unsigned short* MS2b = MS2 + ((size_t)b << 18);
            unsigned v = MS2b[cc];
            unsigned m = v & 255u, sb = v >> 8;
            unsigned evt = (m | sb) & ((2u << ss) - 1u);
            bool dual = false; int bb = 0;
            if (evt) {
                bb = 31 - __builtin_clz(evt);
                dual = (((m >> bb) & 1) != 0) && (((sb >> bb) & 1) != 0);
            }
            if (dual) {
                // r = A - B; A = eval(cc-d, bb-1), B = eval(cc, bb-1)
                if (h == 0) val = bv_eval1_ind(cc - cDG[bb], bb - 1, MS2b, MS1b, ic);
                else        val = bv_eval1_ind(cc, bb - 1, MS2b, MS1b, ic);
            } else if (h == 0) {
                val = bv_eval1_ind(cc, ss, MS2b, MS1b, ic);   // fallback (unreachable)
            }
        } else {                // type B: iter1 value at s (h=1 contributes 0)
            if (h == 0) val = bv_leaf1_1((int)(e.y & 0x3FFFFu), MS1b, ic);
        }
        float partner = __shfl_xor(val, 1);
        if (h == 0) oc[g] = val - partner;   // typeA: A-B; typeB/fallback: v-0
    }
}

// smooth(0.95*v): conv3x3(ones/18, zero-pad) + center*0.5
// -> world ch18,19 AND velocity tail (fused copy; vin is a ws buffer).
__global__ __launch_bounds__(256) void bv_smooth_kernel(
    const float* __restrict__ vin, float* __restrict__ dout)
{
    int idx = blockIdx.x*256 + threadIdx.x;
    if (idx >= BATCH*2*HW) return;
    int x = idx & (WW-1);
    int y = (idx >> 9) & (HH-1);
    int c = (idx >> 18) & 1;
    int b = idx >> 19;
    const float* vb = vin + (size_t)(b*2 + c)*HW;
    const float w18 = (float)(1.0/18.0);
    float acc = 0.0f;
    for (int ky = -1; ky <= 1; ++ky) {
        int yy = y + ky;
        if ((unsigned)yy >= HH) continue;
        for (int kx = -1; kx <= 1; ++kx) {
            int xx2 = x + kx;
            if ((unsigned)xx2 >= WW) continue;
            float s = 0.95f * vb[yy*WW + xx2];
            acc += s * w18;
        }
    }
    float sc = 0.95f * vb[y*WW + x];
    float res = acc + sc * 0.5f;
    dout[((size_t)b*20 + 18 + c)*HW + (size_t)(y<<9) + x] = res;
    dout[(size_t)BATCH*20*HW + (size_t)idx] = res;
}

extern "C" void kernel_launch(void* const* d_in, const int* in_sizes, int n_in,
                              void* d_out, int out_size, void* d_ws, size_t ws_size,
                              hipStream_t stream)
{
    const float* world_in   = (const float*)d_in[0];
    const float* vel_in     = (const float*)d_in[1];
    const float* elem_empty = (const float*)d_in[2];
    float* out = (float*)d_out;

    // ws (~39 MB): w01 | vd1 | vel2 | bk | MS1 | MS2 | Src1 | Src2 | cnt | tlist
    float* w01  = (float*)d_ws;                                // 4*2*HW floats
    float* vd1  = w01 + (size_t)BATCH*2*HW;
    float* vel2 = vd1 + (size_t)BATCH*2*HW;
    unsigned char* bk  = (unsigned char*)(vel2 + (size_t)BATCH*2*HW);
    unsigned short* MS1 = (unsigned short*)(bk + (size_t)BHW);
    unsigned short* MS2 = MS1 + (size_t)BHW;
    int* Src1 = (int*)(MS2 + (size_t)BHW);
    int* Src2 = Src1 + (size_t)BHW;
    unsigned* pcount = (unsigned*)(Src2 + (size_t)BHW);
    uint2* tlistb = (uint2*)(pcount + 16);
    const unsigned listcap = 1u << 18;                         // 256K entries, 2 MB

    dim3 blk(256);
    dim3 grd((BHW + 255)/256);
    dim3 g2((BATCH*2*HW + 255)/256);
    dim3 gA(BATCH*16*16);            // 1024 tile-blocks
    dim3 gB(BHW/8/256, 4);           // 512 x 4 channel-groups
    dim3 gT(2048);                   // tree kernel, grid-stride

    // bucket1 on vel_in; zeroes counters
    bv_bucket_kernel<<<grd, blk, 0, stream>>>(vel_in, bk, pcount);
    // iter1: mask+evolve+vdelta1(vel_in->vd1)+bucket2->bk
    bv_mask_kernel<false><<<gA, dim3(ANT), 0, stream>>>(
        world_in, 20, w01, 2, bk, MS1, Src1,
        vel_in, vd1, bk,
        (const int*)nullptr, pcount, (uint2*)nullptr, 0u, elem_empty);
    // iter2: mask+evolve+vdelta2(vd1->vel2); compose Src2 = P2 o P1
    bv_mask_kernel<true><<<gA, dim3(ANT), 0, stream>>>(
        w01, 2, out, 20, bk, MS2, Src2,
        vd1, vel2, (unsigned char*)nullptr,
        Src1, pcount, tlistb, listcap, elem_empty);
    // passive channels: composed gather pass + rare tree overwrite
    bv_apply_kernel<<<gB, blk, 0, stream>>>(world_in, 20, out, 20, Src2);
    bv_tree_kernel<<<gT, blk, 0, stream>>>(world_in, out, tlistb, pcount,
                                           listcap, MS1, MS2);
    // epilogue: smoothed velocity -> ch18/19 + tail
    bv_smooth_kernel<<<g2, blk, 0, stream>>>(vel2, out);
}

// Round 23
// 159.376 us; speedup vs baseline: 1.2589x; 1.2589x over previous
//
#include <hip/hip_runtime.h>
#include <math.h>

#define HH 512
#define WW 512
#define HW (HH*WW)          // 262144
#define BATCH 4
#define NCH 18              // simulated channels (18,19 overwritten at end)
#define BHW (BATCH*HW)

__device__ __constant__ int cDG[8] = {-512,-511,1,513,512,511,-1,-513}; // dy*WW+dx
__device__ __constant__ int cDT[8] = {-48,-47,1,49,48,47,-1,-49};       // dy*ATP+dx

// bucket (3 bits) | enough (bit 3); zeroes list counter
__global__ __launch_bounds__(256) void bv_bucket_kernel(
    const float* __restrict__ vel, unsigned char* __restrict__ bk,
    unsigned* __restrict__ pcount)
{
    int idx = blockIdx.x*256 + threadIdx.x;
    if (idx == 0) { pcount[0] = 0; pcount[1] = 0; }
    if (idx >= BHW) return;
    int b = idx >> 18;
    int rem = idx & (HW-1);
    const float* vb = vel + (size_t)b*2*HW;
    float vy = vb[rem];
    float vx = vb[HW + rem];
    float a2 = vy*vy;
    float b2 = vx*vx;
    float mag = sqrtf(a2 + b2);
    float xx = vx / (mag + 0.001f);
    float af = (float)acos((double)xx);
    const float inv2pi = (float)(1.0/(2.0*3.14159265358979323846));
    float raw = inv2pi * af;
    float ang = (vy < 0.0f) ? (1.0f - raw) : raw;
    float t = ang * 8.0f + 0.5f;
    int bkt = (int)floorf(t);
    bkt &= 7;
    unsigned char e = (mag > 0.1f) ? (unsigned char)8 : (unsigned char)0;
    bk[idx] = (unsigned char)(bkt | e);
}

#define ATP 48
#define ATC (48*48)   // 2304 = 4*512 + 256
#define ANT 512
#define PAD 49        // max |doff|; pads replace index clamps

// ---- Kernel A: fused mask+evolve+vdelta with PADDED LDS. Emits combined
//      MS = m | (sb<<8), vdelta (exact per-step order), and for iter1 the
//      next-iteration bucket byte. COMPOSE=false (iter1): plain records.
//      COMPOSE=true (iter2): composes with Src1; trees to compacted list.
template<bool COMPOSE>
__global__ __launch_bounds__(ANT) void bv_mask_kernel(
    const float* __restrict__ Win, int Cin,
    float* __restrict__ Wout, int Cout,
    const unsigned char* __restrict__ bkall,
    unsigned short* __restrict__ MSg,
    int* __restrict__ SrcOut,
    const float* __restrict__ velg,    // iteration-start velocity
    float* __restrict__ vdout,         // velocity after this iteration
    unsigned char* __restrict__ bkout, // iter1 only: bucket for iter2
    const int* __restrict__ Src1g,     // COMPOSE only
    unsigned* __restrict__ pcount,     // [1]=tree entries (COMPOSE only)
    uint2* __restrict__ tlist,
    unsigned listcap,
    const float* __restrict__ elem_empty)
{
    // carve: A0|A1|B0|B1 (2402 floats each) | KSH (2402 B) | sCnt
    __shared__ __align__(16) unsigned char SHM[40864];
    float* A0  = ((float*)(SHM +     0)) + PAD;
    float* A1  = ((float*)(SHM +  9608)) + PAD;
    float* B0F = ((float*)(SHM + 19216)) + PAD;
    float* B1F = ((float*)(SHM + 28824)) + PAD;
    unsigned char* KSH = SHM + 38432 + PAD;
    unsigned* sCnt = (unsigned*)(SHM + 40840);

    unsigned char* MSHb = SHM + 19216 + PAD;   // post-steps M bytes (B0F dead)
    unsigned char* SBb  = SHM + 28824 + PAD;   // post-steps SB bytes (B1F dead)

    const int tid = threadIdx.x;
    const int blk = blockIdx.x;
    const int tx = blk & 15, ty = (blk >> 4) & 15, b = blk >> 8;
    const int x0 = tx*32 - 8, y0 = ty*32 - 8;

    const float* inb  = Win  + (size_t)b*Cin*HW;
    float*       outb = Wout + (size_t)b*Cout*HW;
    const unsigned char* bkb = bkall + ((size_t)b << 18);
    unsigned short* MSob = MSg + ((size_t)b << 18);
    int*            Srb  = SrcOut + ((size_t)b << 18);
    const float* velb = velg  + (size_t)b*2*HW;
    float*       vdb  = vdout + (size_t)b*2*HW;

    const float e0 = elem_empty[0];
    const float e1 = elem_empty[1];

    float v0r[4], v1r[4];
    unsigned kreg[4], mreg[4];
    unsigned mtail = 0;

    if (tid == 0) sCnt[0] = 0;

    // ---- load: LDS + register copies for owned cells ----
    #pragma unroll
    for (int k = 0; k < 4; ++k) {
        int l = tid + (k << 9);
        int ly = l / ATP, lx = l - ly*ATP;
        int gy = y0 + ly, gx = x0 + lx;
        bool in = ((unsigned)gy < HH) && ((unsigned)gx < WW);
        int g = gy*WW + gx;
        float v0 = 0.f, v1 = 0.f; unsigned char kk = 0;
        if (in) { v0 = inb[g]; v1 = inb[HW + g]; kk = bkb[g]; }
        A0[l] = v0; A1[l] = v1; KSH[l] = kk;
        v0r[k] = v0; v1r[k] = v1; kreg[k] = kk; mreg[k] = 0;
    }
    if (tid < 256) {    // tail cells: LDS-resident values, register M
        int l = 2048 + tid;
        int ly = l / ATP, lx = l - ly*ATP;
        int gy = y0 + ly, gx = x0 + lx;
        bool in = ((unsigned)gy < HH) && ((unsigned)gx < WW);
        int g = gy*WW + gx;
        float v0 = 0.f, v1 = 0.f; unsigned char kk = 0;
        if (in) { v0 = inb[g]; v1 = inb[HW + g]; kk = bkb[g]; }
        A0[l] = v0; A1[l] = v1; KSH[l] = kk;
    }
    __syncthreads();

    // ---- 8 fused steps, one barrier each; unclamped padded access ----
    #pragma unroll
    for (int a = 0; a < 8; ++a) {
        const int doff = cDT[a];
        const unsigned tgt = (unsigned)(a | 8);
        const float* cA0 = (a & 1) ? B0F : A0;
        const float* cA1 = (a & 1) ? B1F : A1;
        float* nA0 = (a & 1) ? A0 : B0F;
        float* nA1 = (a & 1) ? A1 : B1F;
        #pragma unroll
        for (int k = 0; k < 4; ++k) {
            const int l = tid + (k << 9);
            const int ln = l + doff;
            const int lo = l - doff;
            float a0l = v0r[k], a1l = v1r[k];
            float a0n = cA0[ln];
            float a0o = cA0[lo], a1o = cA1[lo];
            unsigned ko = KSH[lo];
            bool sal = ((kreg[k] & 15u) == tgt) & (a0n > 0.5f) & !(a1l > 0.5f);
            bool sao = ((ko & 15u) == tgt) & (a0l > 0.5f) & !(a1o > 0.5f);
            mreg[k] |= (sal ? 1u : 0u) << a;
            float sa = sal ? 1.0f : 0.0f;
            float sb = sao ? 1.0f : 0.0f;
            float r0 = a0l - sa*a0l; r0 = r0 - sb*a0l; r0 = r0 + sa*e0; r0 = r0 + sb*a0o;
            float r1 = a1l - sa*a1l; r1 = r1 - sb*a1l; r1 = r1 + sa*e1; r1 = r1 + sb*a1o;
            v0r[k] = r0; v1r[k] = r1;
            nA0[l] = r0; nA1[l] = r1;
        }
        if (tid < 256) {
            const int l = 2048 + tid;
            const int ln = l + doff;
            const int lo = l - doff;
            float a0l = cA0[l], a1l = cA1[l];
            float a0n = cA0[ln];
            float a0o = cA0[lo], a1o = cA1[lo];
            unsigned kl = KSH[l], ko = KSH[lo];
            bool sal = ((kl & 15u) == tgt) & (a0n > 0.5f) & !(a1l > 0.5f);
            bool sao = ((ko & 15u) == tgt) & (a0l > 0.5f) & !(a1o > 0.5f);
            if (sal) mtail |= 1u << a;
            float sa = sal ? 1.0f : 0.0f;
            float sb = sao ? 1.0f : 0.0f;
            float r0 = a0l - sa*a0l; r0 = r0 - sb*a0l; r0 = r0 + sa*e0; r0 = r0 + sb*a0o;
            float r1 = a1l - sa*a1l; r1 = r1 - sb*a1l; r1 = r1 + sa*e1; r1 = r1 + sb*a1o;
            nA0[l] = r0; nA1[l] = r1;
        }
        __syncthreads();
    }
    // final ch0/ch1 in A0/A1; B0F/B1F dead -> M/SB byte arrays

    #pragma unroll
    for (int k = 0; k < 4; ++k) MSHb[tid + (k << 9)] = (unsigned char)mreg[k];
    if (tid < 256) MSHb[2048 + tid] = (unsigned char)mtail;
    __syncthreads();

    // SB bits (padded MSHb read, no clamps)
    for (int l = tid; l < ATC; l += ANT) {
        unsigned sb8 = 0;
        #pragma unroll
        for (int a = 0; a < 8; ++a) {
            int lo = l - cDT[a];
            sb8 |= (unsigned)((MSHb[lo] >> a) & 1) << a;
        }
        SBb[l] = (unsigned char)sb8;
    }
    __syncthreads();

    // ---- pass A: interior writes + fused vdelta + walk (+composition) ----
    int tNeed[2]; unsigned tLL[2], tEy[2];
    #pragma unroll
    for (int it = 0; it < 2; ++it) {
        tNeed[it] = 0;
        int li = tid + (it << 9);
        int iy = li >> 5, ix = li & 31;
        int l = (iy + 8)*ATP + ix + 8;
        int gy = ty*32 + iy, gx = tx*32 + ix;
        int g = gy*WW + gx;
        outb[g]      = A0[l];
        outb[HW + g] = A1[l];
        unsigned mm = MSHb[l], sbb = SBb[l];
        MSob[g] = (unsigned short)(mm | (sbb << 8));

        // vdelta (exact per-step op order; vel fixed during iteration)
        {
            float vy = velb[g], vx = velb[HW + g];
            float ddy = vy, ddx = vx;
            unsigned act = mm | sbb;
            if (act) {
                #pragma unroll
                for (int a = 0; a < 8; ++a) {
                    if ((act >> a) & 1) {
                        float sa = (float)((mm  >> a) & 1);
                        float sb = (float)((sbb >> a) & 1);
                        float voy = 0.f, vox = 0.f;
                        if (sb != 0.f) {
                            int go = g - cDG[a];     // in-image when sb=1
                            voy = velb[go]; vox = velb[HW + go];
                        }
                        ddy = ddy - (sa*vy)*0.5f; ddy = ddy + (sb*voy)*0.5f;
                        ddx = ddx - (sa*vx)*0.5f; ddx = ddx + (sb*vox)*0.5f;
                    }
                }
            }
            vdb[g]      = ddy;
            vdb[HW + g] = ddx;
            if constexpr (!COMPOSE) {   // emit iter2 bucket byte
                float a2 = ddy*ddy;
                float b2 = ddx*ddx;
                float mag = sqrtf(a2 + b2);
                float xx = ddx / (mag + 0.001f);
                float af = (float)acos((double)xx);
                const float inv2pi = (float)(1.0/(2.0*3.14159265358979323846));
                float raw = inv2pi * af;
                float ang = (ddy < 0.0f) ? (1.0f - raw) : raw;
                float t = ang * 8.0f + 0.5f;
                int bkt = (int)floorf(t);
                bkt &= 7;
                unsigned char e = (mag > 0.1f) ? (unsigned char)8 : (unsigned char)0;
                bkout[((size_t)b << 18) + g] = (unsigned char)(bkt | e);
            }
        }

        // provenance walk in LDS (in-tile by ring invariant)
        int cc = l, ss = 7, kd = 0;
        unsigned m = mm, sb = sbb;
        while (true) {
            unsigned evt = (m | sb) & ((2u << ss) - 1u);
            if (!evt) { kd = 0; break; }
            int bb = 31 - __builtin_clz(evt);
            int ia = (m >> bb) & 1, ib = (sb >> bb) & 1;
            if (ia && ib) { kd = 2; break; }        // tree at (cc, ss)
            if (ia) { kd = 1; break; }              // e=0 for c>=2 -> ZERO
            cc -= cDT[bb]; ss = bb - 1;             // sb-only: exact value move
            if (ss < 0) { kd = 0; break; }
            m = MSHb[cc]; sb = SBb[cc];
        }
        if (kd == 1) {
            Srb[g] = (int)(1u << 30);
        } else if (kd == 0) {
            int cly = cc / ATP, clx = cc - cly*ATP;
            unsigned s = (unsigned)((y0 + cly)*WW + (x0 + clx));
            if (!COMPOSE) {
                Srb[g] = (int)s;
            } else {
                unsigned r1 = (unsigned)Src1g[((size_t)b << 18) + s];
                unsigned k1 = r1 >> 30;
                if (k1 == 0u)      Srb[g] = (int)r1;        // copy o copy
                else if (k1 == 1u) Srb[g] = (int)(1u << 30);
                else { tNeed[it] = 1; tEy[it] = s; }        // type B: tree1 @ s
            }
        } else {
            if (!COMPOSE) {
                Srb[g] = (int)(2u << 30);   // lazy tree1 marker
            } else {
                int cly = cc / ATP, clx = cc - cly*ATP;
                unsigned ccg = (unsigned)((y0 + cly)*WW + (x0 + clx));
                tNeed[it] = 1;
                tEy[it] = (1u << 31) | ((unsigned)ss << 28) | ccg;   // type A
            }
        }
        if (COMPOSE && tNeed[it]) tLL[it] = atomicAdd(&sCnt[0], 1u);
    }
    if constexpr (COMPOSE) {
        __syncthreads();
        if (tid == 0) sCnt[1] = sCnt[0] ? atomicAdd(&pcount[1], sCnt[0]) : 0u;
        __syncthreads();
        unsigned lbase = sCnt[1];
        #pragma unroll
        for (int it = 0; it < 2; ++it) {
            if (!tNeed[it]) continue;
            int li = tid + (it << 9);
            int iy = li >> 5, ix = li & 31;
            int g = (ty*32 + iy)*WW + tx*32 + ix;
            unsigned lidx = lbase + tLL[it];
            if (lidx < listcap) {
                tlist[lidx] = make_uint2(((unsigned)b << 18) | (unsigned)g, tEy[it]);
                Srb[g] = (int)(2u << 30);           // placeholder
            } else {
                Srb[g] = (int)(3u << 30);           // unreachable (cap 16x margin)
            }
        }
    }
}

// ---- iterative stack-machine evaluator on MS, DIRECT leaves. Depth <= 9.
__device__ __attribute__((noinline)) float bv_eval(
    int cell, int stp,
    const unsigned short* __restrict__ MS,
    const float* __restrict__ initc)
{
    float vstk[10]; int vsp = 0;
    int cs_cell[10], cs_stp[10], cs_ph[10]; int csp = 0;
    cs_cell[0] = cell; cs_stp[0] = stp; cs_ph[0] = 0; csp = 1;
    while (csp > 0) {
        int ph = cs_ph[csp-1];
        if (ph == 0) {
            int cc = cs_cell[csp-1], ss = cs_stp[csp-1];
            float result = 0.0f; int have = 0;
            while (true) {
                if (ss < 0) { result = initc[cc]; have = 1; break; }
                unsigned v = MS[cc];
                unsigned m = v & 255u, sb = v >> 8;
                unsigned evt = (m | sb) & ((2u << ss) - 1u);
                if (!evt) { result = initc[cc]; have = 1; break; }
                int bb = 31 - __builtin_clz(evt);
                int ia = (m >> bb) & 1, ib = (sb >> bb) & 1;
                if (ia && ib) {
                    cs_cell[csp-1] = cc; cs_stp[csp-1] = bb; cs_ph[csp-1] = 1;
                    cs_cell[csp] = cc - cDG[bb]; cs_stp[csp] = bb - 1; cs_ph[csp] = 0; csp++;
                    break;
                }
                if (ia) { result = 0.0f; have = 1; break; }
                cc -= cDG[bb]; ss = bb - 1;
            }
            if (have) { vstk[vsp++] = result; csp--; }
        } else if (ph == 1) {
            cs_ph[csp-1] = 2;
            cs_cell[csp] = cs_cell[csp-1]; cs_stp[csp] = cs_stp[csp-1] - 1;
            cs_ph[csp] = 0; csp++;
        } else {
            float Bv = vstk[--vsp]; float Av = vstk[--vsp];
            vstk[vsp++] = Av - Bv;   // fl(wo - w)
            csp--;
        }
    }
    return vstk[0];
}

// iter1 value at cell L, one channel (walk MS1; rare tree -> bv_eval)
__device__ float bv_leaf1_1(int L,
    const unsigned short* __restrict__ MS1,
    const float* __restrict__ ic)
{
    int cc = L, ss = 7;
    while (true) {
        unsigned v = MS1[cc];
        unsigned m = v & 255u, sb = v >> 8;
        unsigned evt = (m | sb) & ((2u << ss) - 1u);
        if (!evt) break;                        // value = input at cc
        int bb = 31 - __builtin_clz(evt);
        int ia = (m >> bb) & 1, ib = (sb >> bb) & 1;
        if (ia && ib) return bv_eval(cc, bb, MS1, ic);   // tree1
        if (ia) return 0.0f;
        cc -= cDG[bb]; ss = bb - 1;
        if (ss < 0) break;                      // value = input at cc
    }
    return ic[cc];
}

// iterative evaluator on MS2 with leaves INDIRECTED through iter1.
// ss < 0 on entry => pure iter1 value at cell (type-B path).
__device__ float bv_eval1_ind(int cell, int stp,
    const unsigned short* __restrict__ MS2,
    const unsigned short* __restrict__ MS1,
    const float* __restrict__ ic)
{
    float vstk[10]; int vsp = 0;
    int cs_cell[10], cs_stp[10], cs_ph[10]; int csp = 0;
    cs_cell[0] = cell; cs_stp[0] = stp; cs_ph[0] = 0; csp = 1;
    while (csp > 0) {
        int ph = cs_ph[csp-1];
        if (ph == 0) {
            int cc = cs_cell[csp-1], ss = cs_stp[csp-1];
            int have = 0, zero = 0, leaf = 0;
            while (true) {
                if (ss < 0) { leaf = cc; have = 1; break; }
                unsigned v = MS2[cc];
                unsigned m = v & 255u, sb = v >> 8;
                unsigned evt = (m | sb) & ((2u << ss) - 1u);
                if (!evt) { leaf = cc; have = 1; break; }
                int bb = 31 - __builtin_clz(evt);
                int ia = (m >> bb) & 1, ib = (sb >> bb) & 1;
                if (ia && ib) {
                    cs_cell[csp-1] = cc; cs_stp[csp-1] = bb; cs_ph[csp-1] = 1;
                    cs_cell[csp] = cc - cDG[bb]; cs_stp[csp] = bb - 1; cs_ph[csp] = 0; csp++;
                    break;
                }
                if (ia) { zero = 1; have = 1; break; }
                cc -= cDG[bb]; ss = bb - 1;
            }
            if (have) {
                vstk[vsp++] = zero ? 0.0f : bv_leaf1_1(leaf, MS1, ic);
                csp--;
            }
        } else if (ph == 1) {
            cs_ph[csp-1] = 2;
            cs_cell[csp] = cs_cell[csp-1]; cs_stp[csp] = cs_stp[csp-1] - 1;
            cs_ph[csp] = 0; csp++;
        } else {
            float Bv = vstk[--vsp]; float Av = vstk[--vsp];
            vstk[vsp++] = Av - Bv;
            csp--;
        }
    }
    return vstk[0];
}

// ---- Kernel B: apply composed provenance world_in -> out.
//      8 pixels/thread; non-copy lanes write 0 (tree kernel overwrites).
__global__ __launch_bounds__(256) void bv_apply_kernel(
    const float* __restrict__ Win, int Cin,
    float* __restrict__ Wout, int Cout,
    const int* __restrict__ Src)
{
    int t = blockIdx.x*256 + threadIdx.x;   // over BHW/8
    if (t >= BHW/8) return;
    const int c0 = 2 + blockIdx.y*4;        // channel group [c0, c0+4)
    int p = t << 3;
    int b = p >> 18;
    int own = p & (HW-1);
    const float* inb  = Win  + (size_t)b*Cin*HW;
    float*       outb = Wout + (size_t)b*Cout*HW;
    const int* Srb = Src + ((size_t)b << 18);

    int4 sA = *(const int4*)(Srb + own);
    int4 sB = *(const int4*)(Srb + own + 4);
    unsigned sv[8] = {(unsigned)sA.x, (unsigned)sA.y, (unsigned)sA.z, (unsigned)sA.w,
                      (unsigned)sB.x, (unsigned)sB.y, (unsigned)sB.z, (unsigned)sB.w};
    int kind[8], idx[8]; bool need[8];
    bool allself = true;
    #pragma unroll
    for (int j = 0; j < 8; ++j) {
        kind[j] = (int)(sv[j] >> 30);
        idx[j]  = (int)(sv[j] & 0x3FFFFu);
        need[j] = (kind[j] != 0) || (idx[j] != own + j);
        allself = allself && !need[j];
    }

    if (allself) {
        #pragma unroll
        for (int c = 0; c < 4; ++c) {
            const float* ic = inb + (size_t)(c0 + c)*HW;
            float*       oc = outb + (size_t)(c0 + c)*HW;
            float4 va = *(const float4*)(ic + own);
            float4 vb = *(const float4*)(ic + own + 4);
            *(float4*)(oc + own)     = va;
            *(float4*)(oc + own + 4) = vb;
        }
        return;
    }
    #pragma unroll
    for (int c = 0; c < 4; ++c) {
        const float* ic = inb + (size_t)(c0 + c)*HW;
        float*       oc = outb + (size_t)(c0 + c)*HW;
        float4 va = *(const float4*)(ic + own);
        float4 vb = *(const float4*)(ic + own + 4);
        float r[8] = {va.x, va.y, va.z, va.w, vb.x, vb.y, vb.z, vb.w};
        #pragma unroll
        for (int j = 0; j < 8; ++j) {
            if (need[j])
                r[j] = (kind[j] == 0) ? ic[idx[j]] : 0.0f;  // 1/2/3 -> 0 (tree overwrites)
        }
        *(float4*)(oc + own)     = make_float4(r[0], r[1], r[2], r[3]);
        *(float4*)(oc + own + 4) = make_float4(r[4], r[5], r[6], r[7]);
    }
}

// ---- Kernel C: composed tree cells; 32 threads/entry with a SINGLE
//      evaluator call site: divergent (scc,sss) args -> lanes co-execute,
//      wave time = max(A,B) not A+B. Combine A-B via shfl_xor.
__global__ __launch_bounds__(256) void bv_tree_kernel(
    const float* __restrict__ Win,       // world_in, 20-ch
    float* __restrict__ Wout,            // out, 20-ch
    const uint2* __restrict__ tlist,
    const unsigned* __restrict__ pcount, // [1] = entry count
    unsigned listcap,
    const unsigned short* __restrict__ MS1,
    const unsigned short* __restrict__ MS2)
{
    unsigned n = pcount[1]; if (n > listcap) n = listcap;
    unsigned total = n * 32;
    for (unsigned i = blockIdx.x*256 + threadIdx.x; i < total; i += gridDim.x*256) {
        unsigned ei = i >> 5;
        int c = 2 + (int)((i >> 1) & 15);
        int h = (int)(i & 1);
        uint2 e = tlist[ei];
        int b = (int)((e.x >> 18) & 3u);
        int g = (int)(e.x & 0x3FFFFu);
        const float* ic = Win  + (size_t)b*20*HW + (size_t)c*HW;
        float*       oc = Wout + (size_t)b*20*HW + (size_t)c*HW;
        const unsigned short* MS1b = MS1 + ((size_t)b << 18);
        const unsigned short* MS2b = MS2 + ((size_t)b << 18);
        int scc, sss; bool hzero = (h == 1);
        if (e.y >> 31) {        // type A: tree2 at (cc, bound ss)
            int cc = (int)(e.y & 0x3FFFFu);
            int ss = (int)((e.y >> 28) & 7u);
            unsigned v = MS2b[cc];
            unsigned m = v & 255u, sb = v >> 8;
            unsigned evt = (m | sb) & ((2u << ss) - 1u);
            bool dual = false; int bb = 0;
            if (evt) {
                bb = 31 - __builtin_clz(evt);
                dual = (((m >> bb) & 1) != 0) && (((sb >> bb) & 1) != 0);
            }
            if (dual) {
                scc = (h == 0) ? (cc - cDG[bb]) : cc;   // A : B subtree
                sss = bb - 1;
                hzero = false;
            } else {            // unreachable fallback: both eval, odd zeroes
                scc = cc; sss = ss;
            }
        } else {                // type B: iter1 value at s (ss<0 => leaf walk)
            scc = (int)(e.y & 0x3FFFFu); sss = -1;
        }
        float val = bv_eval1_ind(scc, sss, MS2b, MS1b, ic);
        if (hzero) val = 0.0f;
        float partner = __shfl_xor(val, 1);
        if (h == 0) oc[g] = val - partner;   // dual: A-B; else: v-0 = v
    }
}

// smooth(0.95*v): conv3x3(ones/18, zero-pad) + center*0.5
// -> world ch18,19 AND velocity tail (fused copy; vin is a ws buffer).
__global__ __launch_bounds__(256) void bv_smooth_kernel(
    const float* __restrict__ vin, float* __restrict__ dout)
{
    int idx = blockIdx.x*256 + threadIdx.x;
    if (idx >= BATCH*2*HW) return;
    int x = idx & (WW-1);
    int y = (idx >> 9) & (HH-1);
    int c = (idx >> 18) & 1;
    int b = idx >> 19;
    const float* vb = vin + (size_t)(b*2 + c)*HW;
    const float w18 = (float)(1.0/18.0);
    float acc = 0.0f;
    for (int ky = -1; ky <= 1; ++ky) {
        int yy = y + ky;
        if ((unsigned)yy >= HH) continue;
        for (int kx = -1; kx <= 1; ++kx) {
            int xx2 = x + kx;
            if ((unsigned)xx2 >= WW) continue;
            float s = 0.95f * vb[yy*WW + xx2];
            acc += s * w18;
        }
    }
    float sc = 0.95f * vb[y*WW + x];
    float res = acc + sc * 0.5f;
    dout[((size_t)b*20 + 18 + c)*HW + (size_t)(y<<9) + x] = res;
    dout[(size_t)BATCH*20*HW + (size_t)idx] = res;
}

extern "C" void kernel_launch(void* const* d_in, const int* in_sizes, int n_in,
                              void* d_out, int out_size, void* d_ws, size_t ws_size,
                              hipStream_t stream)
{
    const float* world_in   = (const float*)d_in[0];
    const float* vel_in     = (const float*)d_in[1];
    const float* elem_empty = (const float*)d_in[2];
    float* out = (float*)d_out;

    // ws (~39 MB): w01 | vd1 | vel2 | bk | MS1 | MS2 | Src1 | Src2 | cnt | tlist
    float* w01  = (float*)d_ws;                                // 4*2*HW floats
    float* vd1  = w01 + (size_t)BATCH*2*HW;
    float* vel2 = vd1 + (size_t)BATCH*2*HW;
    unsigned char* bk  = (unsigned char*)(vel2 + (size_t)BATCH*2*HW);
    unsigned short* MS1 = (unsigned short*)(bk + (size_t)BHW);
    unsigned short* MS2 = MS1 + (size_t)BHW;
    int* Src1 = (int*)(MS2 + (size_t)BHW);
    int* Src2 = Src1 + (size_t)BHW;
    unsigned* pcount = (unsigned*)(Src2 + (size_t)BHW);
    uint2* tlistb = (uint2*)(pcount + 16);
    const unsigned listcap = 1u << 18;                         // 256K entries, 2 MB

    dim3 blk(256);
    dim3 grd((BHW + 255)/256);
    dim3 g2((BATCH*2*HW + 255)/256);
    dim3 gA(BATCH*16*16);            // 1024 tile-blocks
    dim3 gB(BHW/8/256, 4);           // 512 x 4 channel-groups
    dim3 gT(2048);                   // tree kernel, grid-stride

    // bucket1 on vel_in; zeroes counters
    bv_bucket_kernel<<<grd, blk, 0, stream>>>(vel_in, bk, pcount);
    // iter1: mask+evolve+vdelta1(vel_in->vd1)+bucket2->bk
    bv_mask_kernel<false><<<gA, dim3(ANT), 0, stream>>>(
        world_in, 20, w01, 2, bk, MS1, Src1,
        vel_in, vd1, bk,
        (const int*)nullptr, pcount, (uint2*)nullptr, 0u, elem_empty);
    // iter2: mask+evolve+vdelta2(vd1->vel2); compose Src2 = P2 o P1
    bv_mask_kernel<true><<<gA, dim3(ANT), 0, stream>>>(
        w01, 2, out, 20, bk, MS2, Src2,
        vd1, vel2, (unsigned char*)nullptr,
        Src1, pcount, tlistb, listcap, elem_empty);
    // passive channels: composed gather pass + rare tree overwrite
    bv_apply_kernel<<<gB, blk, 0, stream>>>(world_in, 20, out, 20, Src2);
    bv_tree_kernel<<<gT, blk, 0, stream>>>(world_in, out, tlistb, pcount,
                                           listcap, MS1, MS2);
    // epilogue: smoothed velocity -> ch18/19 + tail
    bv_smooth_kernel<<<g2, blk, 0, stream>>>(vel2, out);
}